// Round 1
// baseline (63888.879 us; speedup 1.0000x reference)
//
#include <hip/hip_runtime.h>
#include <math.h>
#include <stdint.h>

// ---------------------------------------------------------------------------
// Speller decoder: 64 sequential steps of {LSTM cell -> 4-head dot attention
// over T=1024 -> ReLU MLP -> logits/log_softmax/argmax feedback}.
// Persistent-kernel design: 512 blocks x 256 threads, custom hierarchical
// device-wide barrier (4 per step). Weights live in LDS (preloaded once).
// All math fp32 (argmax feedback is precision-sensitive).
// ---------------------------------------------------------------------------

#define NB 512
#define NT 256

constexpr int Bv = 32, Tv = 1024, Hv = 512, Vv = 5000, STEPS = 64;
constexpr int K1 = 1536;              // E(512 emb) + F(512 ctx) + H(512 h)

// ---- u32 counter region of ws (padded to cache lines) ----
constexpr int MCNT = 0;               // master barrier counter
constexpr int GEN  = 16;              // barrier generation
constexpr int GCNT = 32;              // 32 group counters, stride 16
constexpr int ACNT = 1024;            // 32 attention-merge counters, stride 16
constexpr int LCNT = 1536;            // 32 logits-merge counters, stride 16
constexpr int WSU  = 2048;            // u32 region size

// ---- float region offsets (relative to wsf = (float*)ws + WSU) ----
constexpr int XH     = 0;                      // [32][1536] = emb | ctx | h
constexpr int CBUF   = XH + 32*1536;           // [2][32][512] LSTM cell state
constexpr int GATES  = CBUF + 2*32*512;        // [32][2048]
constexpr int HID    = GATES + 32*2048;        // [32][512]
constexpr int LOGITS = HID + 32*512;           // [32][5120]
constexpr int PART   = LOGITS + 32*5120;       // [32][4][16][130] attn partials
constexpr int E3     = PART + 32*4*16*130;     // [32][1024] head-3 energies
constexpr int PM     = E3 + 32*1024;           // [32][256] chunk max
constexpr int PSUM   = PM + 32*256;            // [32][256] chunk sumexp
constexpr int PIDX   = PSUM + 32*256;          // [32][256] chunk argmax (int)
constexpr int MB_    = PIDX + 32*256;          // [32] global max
constexpr int LSB_   = MB_ + 32;               // [32] log-sum-exp

__device__ __forceinline__ float sigm(float x) { return 1.f / (1.f + expf(-x)); }

// Hierarchical device barrier: group(16) -> master(32) -> generation bump.
// Writers drain stores at __syncthreads (compiler emits waitcnt before
// s_barrier); tid0's __threadfence() gives agent-scope release/acquire
// (L2 writeback / L1+L2 invalidate) so cross-XCD visibility holds.
__device__ __forceinline__ void gsync(unsigned* wsu, int blk, int tid) {
  __syncthreads();
  if (tid == 0) {
    __threadfence();
    unsigned g = __hip_atomic_load(&wsu[GEN], __ATOMIC_RELAXED, __HIP_MEMORY_SCOPE_AGENT);
    int grp = blk >> 4;
    unsigned o = __hip_atomic_fetch_add(&wsu[GCNT + grp*16], 1u, __ATOMIC_ACQ_REL, __HIP_MEMORY_SCOPE_AGENT);
    if (o == 15u) {
      __hip_atomic_store(&wsu[GCNT + grp*16], 0u, __ATOMIC_RELAXED, __HIP_MEMORY_SCOPE_AGENT);
      unsigned o2 = __hip_atomic_fetch_add(&wsu[MCNT], 1u, __ATOMIC_ACQ_REL, __HIP_MEMORY_SCOPE_AGENT);
      if (o2 == 31u) {
        __hip_atomic_store(&wsu[MCNT], 0u, __ATOMIC_RELAXED, __HIP_MEMORY_SCOPE_AGENT);
        __hip_atomic_fetch_add(&wsu[GEN], 1u, __ATOMIC_RELEASE, __HIP_MEMORY_SCOPE_AGENT);
      }
    }
    while (__hip_atomic_load(&wsu[GEN], __ATOMIC_ACQUIRE, __HIP_MEMORY_SCOPE_AGENT) == g) {
      __builtin_amdgcn_s_sleep(1);
    }
    __threadfence();
  }
  __syncthreads();
}

__global__ void speller_init(const float* __restrict__ LF, const float* __restrict__ Emb,
                             float* __restrict__ wsf, unsigned* __restrict__ wsu) {
  int b = blockIdx.x;
  for (int i = threadIdx.x; i < 512; i += NT) {
    wsf[XH + b*1536 + i]        = Emb[i];                    // embedding row 0
    wsf[XH + b*1536 + 512 + i]  = LF[(size_t)b*Tv*512 + i];  // LF[b,0,:] as ctx0
    wsf[XH + b*1536 + 1024 + i] = 0.f;                       // h0
    wsf[CBUF + b*512 + i]       = 0.f;                       // c0 (buffer 0)
  }
  if (b == 0) for (int i = threadIdx.x; i < WSU; i += NT) wsu[i] = 0u;
}

struct LdsA { float Wg[8][1536]; float gb[8]; };                          // gate blocks
struct LdsB { float Wc[20][512]; float Wp[2][1024]; float bcl[20]; float bpl[2]; };
union  LdsU { LdsA a; LdsB b; };

__launch_bounds__(NT, 2)
__global__ void speller_main(const float* __restrict__ LF, const float* __restrict__ Emb,
                             const float* __restrict__ Wih, const float* __restrict__ Whh,
                             const float* __restrict__ bih, const float* __restrict__ bhh,
                             const float* __restrict__ Wp,  const float* __restrict__ bp,
                             const float* __restrict__ Wc,  const float* __restrict__ bc,
                             float* __restrict__ out, unsigned* __restrict__ wsu,
                             float* __restrict__ wsf) {
  const int blk = blockIdx.x, tid = threadIdx.x;
  __shared__ LdsU lds;
  __shared__ float scr[784];
  __shared__ int  sint[300];

  // ---------------- one-time LDS weight preload ----------------
  if (blk < 256) {
    const int j0 = blk * 8;
    for (int idx = tid; idx < 8*1536; idx += NT) {
      int r = idx / 1536, k = idx - r*1536;
      lds.a.Wg[r][k] = (k < 1024) ? Wih[(size_t)(j0+r)*1024 + k]
                                  : Whh[(size_t)(j0+r)*512 + (k-1024)];
    }
    if (tid < 8) lds.a.gb[tid] = bih[j0+tid] + bhh[j0+tid];
  } else {
    const int blk2 = blk - 256, v0 = blk2*20, rp0 = blk2*2;
    if (v0 < Vv) {
      for (int idx = tid; idx < 20*512; idx += NT) {
        int vi = idx >> 9, k = idx & 511;
        lds.b.Wc[vi][k] = Wc[(size_t)(v0+vi)*512 + k];
      }
      if (tid < 20) lds.b.bcl[tid] = bc[v0+tid];
    }
    for (int idx = tid; idx < 2048; idx += NT) {
      int r = idx >> 10, k = idx & 1023;
      lds.b.Wp[r][k] = Wp[(size_t)(rp0+r)*1024 + k];
    }
    if (tid < 2) lds.b.bpl[tid] = bp[rp0+tid];
  }
  __syncthreads();

#pragma unroll 1
  for (int s = 0; s < STEPS; ++s) {
    // ============ Phase 1: gates GEMM (blocks<256) | finalize prev (>=256) ====
    if (blk < 256) {
      const int j0 = blk * 8;
      const int slot = tid >> 5;       // b-quad group 0..7
      const int ks = tid & 31;         // K split: 48 elems each
      const int b0 = slot * 4;
      float acc[8][4];
#pragma unroll
      for (int r = 0; r < 8; ++r)
#pragma unroll
        for (int i = 0; i < 4; ++i) acc[r][i] = 0.f;
      const float4* xh4 = (const float4*)(wsf + XH);
#pragma unroll
      for (int q = 0; q < 12; ++q) {
        const int kq = ks*12 + q;      // float4 index in 384-wide row
        float4 xv[4];
#pragma unroll
        for (int i = 0; i < 4; ++i) xv[i] = xh4[(size_t)(b0+i)*384 + kq];
#pragma unroll
        for (int r = 0; r < 8; ++r) {
          float4 wv = *(const float4*)(&lds.a.Wg[r][kq*4]);
#pragma unroll
          for (int i = 0; i < 4; ++i)
            acc[r][i] += wv.x*xv[i].x + wv.y*xv[i].y + wv.z*xv[i].z + wv.w*xv[i].w;
        }
      }
#pragma unroll
      for (int r = 0; r < 8; ++r)
#pragma unroll
        for (int i = 0; i < 4; ++i) {
          float v = acc[r][i];
          v += __shfl_xor(v, 16); v += __shfl_xor(v, 8); v += __shfl_xor(v, 4);
          v += __shfl_xor(v, 2);  v += __shfl_xor(v, 1);
          acc[r][i] = v;
        }
      if (ks == 0) {
#pragma unroll
        for (int r = 0; r < 8; ++r)
#pragma unroll
          for (int i = 0; i < 4; ++i)
            wsf[GATES + (size_t)(b0+i)*2048 + j0 + r] = acc[r][i] + lds.a.gb[r];
      }
    } else if (s > 0) {
      const int blk2 = blk - 256, v0 = blk2*20;
      if (v0 < Vv) {
        for (int i = tid; i < 640; i += NT) {
          int b = i / 20, vi = i - b*20;
          out[(size_t)(s-1)*160000 + (size_t)b*5000 + v0 + vi] =
              wsf[LOGITS + (size_t)b*5120 + v0 + vi] - wsf[MB_ + b] - wsf[LSB_ + b];
        }
      }
    }
    gsync(wsu, blk, tid);

    // ============ Phase 2: LSTM pointwise + attention (all 512 blocks) =======
    {
      const int b = blk >> 4, tc = blk & 15;
      float* hs = scr;  // [512]
      const size_t gbase = GATES + (size_t)b*2048;
      const int cr = CBUF + (s & 1)*16384 + b*512;
      const int cw = CBUF + ((s & 1) ^ 1)*16384 + b*512;
      for (int u = tid; u < 512; u += NT) {
        float gi = wsf[gbase + u],        gf = wsf[gbase + 512 + u];
        float gg = wsf[gbase + 1024 + u], go = wsf[gbase + 1536 + u];
        float co = wsf[cr + u];
        float cn = sigm(gf)*co + sigm(gi)*tanhf(gg);
        float hn = sigm(go)*tanhf(cn);
        hs[u] = hn;
        if (tc == 0) { wsf[cw + u] = cn; wsf[XH + (size_t)b*1536 + 1024 + u] = hn; }
      }
      __syncthreads();
      const int w = tid >> 6, ln = tid & 63;   // wave<->head, lane<->t
      const int t0 = tc * 64;
      float e = 0.f;
      {
        const float4* lf4 = (const float4*)(LF + ((size_t)(b*Tv + t0 + ln))*512 + w*128);
        const float4* h4  = (const float4*)(hs + w*128);
#pragma unroll
        for (int q = 0; q < 32; ++q) {
          float4 f = lf4[q]; float4 hh = h4[q];
          e += f.x*hh.x + f.y*hh.y + f.z*hh.z + f.w*hh.w;
        }
      }
      float m = e;
#pragma unroll
      for (int off = 32; off; off >>= 1) m = fmaxf(m, __shfl_xor(m, off));
      float p = expf(e - m);
      float l = p;
#pragma unroll
      for (int off = 32; off; off >>= 1) l += __shfl_xor(l, off);
      scr[512 + w*64 + ln] = p;
      if (w == 3) wsf[E3 + (size_t)b*1024 + t0 + ln] = e;
      // ctx pass: lane <-> d-pair (coalesced LF re-read, mostly L1/L2 hits)
      float c0 = 0.f, c1 = 0.f;
      {
        const float2* lf2 = (const float2*)LF;
        const size_t base2 = (size_t)(b*Tv + t0)*256 + w*64 + ln;
#pragma unroll 8
        for (int i = 0; i < 64; ++i) {
          float pp = scr[512 + w*64 + i];
          float2 f = lf2[base2 + (size_t)i*256];
          c0 += pp*f.x; c1 += pp*f.y;
        }
      }
      float* pr = wsf + PART + (size_t)((b*4 + w)*16 + tc)*130;
      ((float2*)(pr + 2))[ln] = make_float2(c0, c1);
      if (ln == 0) { pr[0] = m; pr[1] = l; }
      __syncthreads();
      if (tid == 0) {
        __threadfence();
        unsigned old = atomicAdd(&wsu[ACNT + b*16], 1u);
        sint[0] = (old == 15u);
      }
      __syncthreads();
      if (sint[0]) {                       // last arriver merges the 16 chunks
        if (tid == 0) __threadfence();
        __syncthreads();
        const int w2 = tid >> 6, ln2 = tid & 63;
        const size_t pb = PART + (size_t)(b*4 + w2)*16*130;
        float M = -1e30f;
#pragma unroll
        for (int i = 0; i < 16; ++i) M = fmaxf(M, wsf[pb + i*130]);
        float L = 0.f;
#pragma unroll
        for (int i = 0; i < 16; ++i) L += wsf[pb + i*130 + 1] * expf(wsf[pb + i*130] - M);
        float cc0 = 0.f, cc1 = 0.f;
#pragma unroll
        for (int i = 0; i < 16; ++i) {
          float sc = expf(wsf[pb + i*130] - M);
          float2 cx = ((const float2*)(wsf + pb + i*130 + 2))[ln2];
          cc0 += sc*cx.x; cc1 += sc*cx.y;
        }
        float invL = 1.f / L;
        ((float2*)(wsf + XH + (size_t)b*1536 + 512 + w2*128))[ln2] = make_float2(cc0*invL, cc1*invL);
        if (ln2 == 0) { scr[768 + w2*2] = M; scr[769 + w2*2] = L; }
        __syncthreads();
        float M3 = scr[768 + 6], iL3 = 1.f / scr[768 + 7];
        for (int i = tid; i < 1024; i += NT)
          out[(size_t)10240000 + ((size_t)(s*32 + b))*1024 + i] =
              expf(wsf[E3 + (size_t)b*1024 + i] - M3) * iL3;
        if (tid == 0)
          __hip_atomic_store(&wsu[ACNT + b*16], 0u, __ATOMIC_RELAXED, __HIP_MEMORY_SCOPE_AGENT);
      }
    }
    gsync(wsu, blk, tid);

    // ============ Phase 3: MLP hid = relu([h,ctx] @ Wp^T + bp) ===============
    if (blk >= 256) {
      const int blk2 = blk - 256, rp0 = blk2*2;
      const int bb = tid & 31, ks = tid >> 5;        // 8 K-windows of 128
      const int kb = ks * 128;
      const int xbase = (ks < 4) ? (1024 + kb) : kb; // concat: k<512 -> h, else ctx
      const float4* xr = (const float4*)(wsf + XH + (size_t)bb*1536 + xbase);
      const float4* w0 = (const float4*)(&lds.b.Wp[0][kb]);
      const float4* w1 = (const float4*)(&lds.b.Wp[1][kb]);
      float a0 = 0.f, a1 = 0.f;
#pragma unroll
      for (int q = 0; q < 32; ++q) {
        float4 xv = xr[q]; float4 wv0 = w0[q], wv1 = w1[q];
        a0 += wv0.x*xv.x + wv0.y*xv.y + wv0.z*xv.z + wv0.w*xv.w;
        a1 += wv1.x*xv.x + wv1.y*xv.y + wv1.z*xv.z + wv1.w*xv.w;
      }
      scr[ks*32 + bb] = a0; scr[256 + ks*32 + bb] = a1;
      __syncthreads();
      if (tid < 64) {
        int r = tid >> 5, b2 = tid & 31;
        float ssum = 0.f;
#pragma unroll
        for (int j = 0; j < 8; ++j) ssum += scr[r*256 + j*32 + b2];
        ssum += lds.b.bpl[r];
        wsf[HID + (size_t)b2*512 + rp0 + r] = fmaxf(ssum, 0.f);
      }
      __syncthreads();
    }
    gsync(wsu, blk, tid);

    // ============ Phase 4: logits + log-softmax/argmax partials + merge ======
    if (blk >= 256) {
      const int blk2 = blk - 256;
      if (blk2 < 250) {
        const int v0 = blk2 * 20;
        const int bb = tid >> 3, ks = tid & 7;       // lane<->K-window of 64
        float4 xr[16];
        const float4* hb = (const float4*)(wsf + HID + (size_t)bb*512 + ks*64);
#pragma unroll
        for (int q = 0; q < 16; ++q) xr[q] = hb[q];
        float lgv[20];
#pragma unroll
        for (int vi = 0; vi < 20; ++vi) {
          float a = 0.f;
          const float4* wr = (const float4*)(&lds.b.Wc[vi][ks*64]);
#pragma unroll
          for (int q = 0; q < 16; ++q) {
            float4 wv = wr[q];
            a += wv.x*xr[q].x + wv.y*xr[q].y + wv.z*xr[q].z + wv.w*xr[q].w;
          }
          a += __shfl_xor(a, 1); a += __shfl_xor(a, 2); a += __shfl_xor(a, 4);
          lgv[vi] = a + lds.b.bcl[vi];
        }
        if (ks == 0) {
#pragma unroll
          for (int vi = 0; vi < 20; ++vi)
            wsf[LOGITS + (size_t)bb*5120 + v0 + vi] = lgv[vi];
        }
        float mych = lgv[0]; int ami = 0;
#pragma unroll
        for (int vi = 1; vi < 20; ++vi)
          if (lgv[vi] > mych) { mych = lgv[vi]; ami = vi; }
        float sume = 0.f;
#pragma unroll
        for (int vi = 0; vi < 20; ++vi) sume += expf(lgv[vi] - mych);
        if (ks == 0) {
          wsf[PM + bb*256 + blk2] = mych;
          wsf[PSUM + bb*256 + blk2] = sume;
          ((int*)(wsf + PIDX))[bb*256 + blk2] = v0 + ami;
        }
      }
      __syncthreads();
      if (tid == 0) __threadfence();
      __syncthreads();
      if (tid < 32) {
        unsigned old = 0xffffffffu;
        if (blk2 < 250) old = atomicAdd(&wsu[LCNT + tid*16], 1u);
        sint[1 + tid] = (old == 249u);
      }
      __syncthreads();
      for (int b2 = 0; b2 < 32; ++b2) {
        if (sint[1 + b2]) {                 // last arriver for batch b2 merges
          if (tid == 0) __threadfence();
          __syncthreads();
          float mv = -1e30f, sv = 0.f; int iv = 0x7fffffff;
          if (tid < 250) {
            mv = wsf[PM + b2*256 + tid];
            sv = wsf[PSUM + b2*256 + tid];
            iv = ((const int*)(wsf + PIDX))[b2*256 + tid];
          }
          scr[tid] = mv; sint[40 + tid] = iv;
          __syncthreads();
          for (int off = 128; off; off >>= 1) {
            if (tid < off) {
              float m2 = scr[tid + off]; int i2 = sint[40 + tid + off];
              if (m2 > scr[tid] || (m2 == scr[tid] && i2 < sint[40 + tid])) {
                scr[tid] = m2; sint[40 + tid] = i2;
              }
            }
            __syncthreads();
          }
          float M = scr[0]; int tok = sint[40];
          __syncthreads();
          scr[tid] = sv * expf(mv - M);
          __syncthreads();
          for (int off = 128; off; off >>= 1) {
            if (tid < off) scr[tid] += scr[tid + off];
            __syncthreads();
          }
          if (tid == 0) { wsf[MB_ + b2] = M; wsf[LSB_ + b2] = logf(scr[0]); }
          for (int i = tid; i < 512; i += NT)
            wsf[XH + (size_t)b2*1536 + i] = Emb[(size_t)tok*512 + i];
          if (tid == 0)
            __hip_atomic_store(&wsu[LCNT + b2*16], 0u, __ATOMIC_RELAXED, __HIP_MEMORY_SCOPE_AGENT);
          __syncthreads();
        }
      }
    }
    gsync(wsu, blk, tid);
  }

  // ---------------- epilogue: finalize step 63's log-softmax ----------------
  if (blk >= 256) {
    const int blk2 = blk - 256, v0 = blk2*20;
    if (v0 < Vv) {
      for (int i = tid; i < 640; i += NT) {
        int b = i / 20, vi = i - b*20;
        out[(size_t)63*160000 + (size_t)b*5000 + v0 + vi] =
            wsf[LOGITS + (size_t)b*5120 + v0 + vi] - wsf[MB_ + b] - wsf[LSB_ + b];
      }
    }
  }
}

extern "C" void kernel_launch(void* const* d_in, const int* in_sizes, int n_in,
                              void* d_out, int out_size, void* d_ws, size_t ws_size,
                              hipStream_t stream) {
  (void)in_sizes; (void)n_in; (void)out_size; (void)ws_size;
  const float* LF  = (const float*)d_in[0];
  const float* Emb = (const float*)d_in[1];
  const float* Wih = (const float*)d_in[2];
  const float* Whh = (const float*)d_in[3];
  const float* bih = (const float*)d_in[4];
  const float* bhh = (const float*)d_in[5];
  const float* Wp  = (const float*)d_in[6];
  const float* bp  = (const float*)d_in[7];
  const float* Wc  = (const float*)d_in[8];
  const float* bc  = (const float*)d_in[9];
  float* out = (float*)d_out;
  unsigned* wsu = (unsigned*)d_ws;
  float* wsf = (float*)d_ws + WSU;

  speller_init<<<32, NT, 0, stream>>>(LF, Emb, wsf, wsu);
  speller_main<<<NB, NT, 0, stream>>>(LF, Emb, Wih, Whh, bih, bhh, Wp, bp, Wc, bc,
                                      out, wsu, wsf);
}

// Round 2
// 18269.054 us; speedup vs baseline: 3.4971x; 3.4971x over previous
//
#include <hip/hip_runtime.h>
#include <math.h>
#include <stdint.h>

// ---------------------------------------------------------------------------
// Speller decoder: 64 sequential steps of {LSTM cell -> 4-head dot attention
// over T=1024 -> ReLU MLP -> logits/log_softmax/argmax feedback}.
// Persistent-kernel design: 512 blocks x 256 threads, custom hierarchical
// device-wide barrier (4 per step). Weights live in LDS (preloaded once).
// All math fp32 (argmax feedback is precision-sensitive).
//
// R2: barrier rework — RELAXED polling (no per-iteration buffer_inv!),
// exactly one release fence on arrival + one acquire fence on exit per
// block, two-level release (leaders poll GEN, members poll group flag),
// monotonic counters (no resets). Phase-1 LDS/global indexing fixed
// (lane-stride 48 floats -> 16-way bank conflicts + 64-line global splits;
// now kq = q*32+ks -> conflict-free + coalesced).
// ---------------------------------------------------------------------------

#define NB 512
#define NT 256

constexpr int Bv = 32, Tv = 1024, Hv = 512, Vv = 5000, STEPS = 64;

// ---- u32 counter region of ws (monotonic counters, padded) ----
constexpr int MCNT = 0;               // master barrier counter (monotonic)
constexpr int GEN  = 16;              // barrier generation (monotonic)
constexpr int GCNT = 64;              // 32 group counters, stride 16 (monotonic)
constexpr int GFLG = 1024;            // 32 group release flags, stride 32
constexpr int ACNT = 2048;            // 32 attn-merge counters, stride 16 (monotonic)
constexpr int LCNT = 2560;            // 32 logits-merge counters, stride 16 (monotonic)
constexpr int WSU  = 4096;            // u32 region size

// ---- float region offsets (relative to wsf = (float*)ws + WSU) ----
constexpr int XH     = 0;                      // [32][1536] = emb | ctx | h
constexpr int CBUF   = XH + 32*1536;           // [2][32][512] LSTM cell state
constexpr int GATES  = CBUF + 2*32*512;        // [32][2048]
constexpr int HID    = GATES + 32*2048;        // [32][512]
constexpr int LOGITS = HID + 32*512;           // [32][5120]
constexpr int PART   = LOGITS + 32*5120;       // [32][4][16][130] attn partials
constexpr int E3     = PART + 32*4*16*130;     // [32][1024] head-3 energies
constexpr int PM     = E3 + 32*1024;           // [32][256] chunk max
constexpr int PSUM   = PM + 32*256;            // [32][256] chunk sumexp
constexpr int PIDX   = PSUM + 32*256;          // [32][256] chunk argmax (int)
constexpr int MB_    = PIDX + 32*256;          // [32] global max
constexpr int LSB_   = MB_ + 32;               // [32] log-sum-exp

__device__ __forceinline__ float sigm(float x) { return 1.f / (1.f + expf(-x)); }

__device__ __forceinline__ unsigned ld_rlx(unsigned* p) {
  return __hip_atomic_load(p, __ATOMIC_RELAXED, __HIP_MEMORY_SCOPE_AGENT);
}
__device__ __forceinline__ void st_rlx(unsigned* p, unsigned v) {
  __hip_atomic_store(p, v, __ATOMIC_RELAXED, __HIP_MEMORY_SCOPE_AGENT);
}
__device__ __forceinline__ unsigned add_rlx(unsigned* p, unsigned v) {
  return __hip_atomic_fetch_add(p, v, __ATOMIC_RELAXED, __HIP_MEMORY_SCOPE_AGENT);
}

// Device barrier. Release fence (wbL2+waitcnt) once on arrival, relaxed
// spin (no cache ops), acquire fence (invL1/L2) once on exit. Monotonic
// counters: barrier #n (1-based) completes when GCNT[g]==16n and MCNT==32n.
__device__ __forceinline__ void gsync(unsigned* wsu, int blk, int tid, unsigned& myGen) {
  __syncthreads();
  if (tid == 0) {
    const unsigned target = ++myGen;
    const int grp = blk >> 4;
    __builtin_amdgcn_fence(__ATOMIC_RELEASE, "agent");       // wbL2 + waitcnt, once
    unsigned o = add_rlx(&wsu[GCNT + grp*16], 1u);
    if (o == target*16u - 1u) {
      unsigned o2 = add_rlx(&wsu[MCNT], 1u);
      if (o2 == target*32u - 1u)
        st_rlx(&wsu[GEN], target);
    }
    if ((blk & 15) == 0) {
      while (ld_rlx(&wsu[GEN]) != target) __builtin_amdgcn_s_sleep(2);
      st_rlx(&wsu[GFLG + grp*32], target);
    } else {
      while (ld_rlx(&wsu[GFLG + grp*32]) != target) __builtin_amdgcn_s_sleep(2);
    }
    __builtin_amdgcn_fence(__ATOMIC_ACQUIRE, "agent");       // invL1+L2, once
  }
  __syncthreads();
}

__global__ void speller_init(const float* __restrict__ LF, const float* __restrict__ Emb,
                             float* __restrict__ wsf, unsigned* __restrict__ wsu) {
  int b = blockIdx.x;
  for (int i = threadIdx.x; i < 512; i += NT) {
    wsf[XH + b*1536 + i]        = Emb[i];                    // embedding row 0
    wsf[XH + b*1536 + 512 + i]  = LF[(size_t)b*Tv*512 + i];  // LF[b,0,:] as ctx0
    wsf[XH + b*1536 + 1024 + i] = 0.f;                       // h0
    wsf[CBUF + b*512 + i]       = 0.f;                       // c0 (buffer 0)
  }
  if (b == 0) for (int i = threadIdx.x; i < WSU; i += NT) wsu[i] = 0u;
}

struct LdsA { float Wg[8][1536]; float gb[8]; };                          // gate blocks
struct LdsB { float Wc[20][512]; float Wp[2][1024]; float bcl[20]; float bpl[2]; };
union  LdsU { LdsA a; LdsB b; };

__launch_bounds__(NT, 2)
__global__ void speller_main(const float* __restrict__ LF, const float* __restrict__ Emb,
                             const float* __restrict__ Wih, const float* __restrict__ Whh,
                             const float* __restrict__ bih, const float* __restrict__ bhh,
                             const float* __restrict__ Wp,  const float* __restrict__ bp,
                             const float* __restrict__ Wc,  const float* __restrict__ bc,
                             float* __restrict__ out, unsigned* __restrict__ wsu,
                             float* __restrict__ wsf) {
  const int blk = blockIdx.x, tid = threadIdx.x;
  unsigned myGen = 0;
  __shared__ LdsU lds;
  __shared__ float scr[784];
  __shared__ int  sint[300];

  // ---------------- one-time LDS weight preload ----------------
  if (blk < 256) {
    const int j0 = blk * 8;
    for (int idx = tid; idx < 8*1536; idx += NT) {
      int r = idx / 1536, k = idx - r*1536;
      lds.a.Wg[r][k] = (k < 1024) ? Wih[(size_t)(j0+r)*1024 + k]
                                  : Whh[(size_t)(j0+r)*512 + (k-1024)];
    }
    if (tid < 8) lds.a.gb[tid] = bih[j0+tid] + bhh[j0+tid];
  } else {
    const int blk2 = blk - 256, v0 = blk2*20, rp0 = blk2*2;
    if (v0 < Vv) {
      for (int idx = tid; idx < 20*512; idx += NT) {
        int vi = idx >> 9, k = idx & 511;
        lds.b.Wc[vi][k] = Wc[(size_t)(v0+vi)*512 + k];
      }
      if (tid < 20) lds.b.bcl[tid] = bc[v0+tid];
    }
    for (int idx = tid; idx < 2048; idx += NT) {
      int r = idx >> 10, k = idx & 1023;
      lds.b.Wp[r][k] = Wp[(size_t)(rp0+r)*1024 + k];
    }
    if (tid < 2) lds.b.bpl[tid] = bp[rp0+tid];
  }
  __syncthreads();

#pragma unroll 1
  for (int s = 0; s < STEPS; ++s) {
    // ============ Phase 1: gates GEMM (blocks<256) | finalize prev (>=256) ====
    if (blk < 256) {
      const int j0 = blk * 8;
      const int slot = tid >> 5;       // b-quad group 0..7
      const int ks = tid & 31;         // K split, interleaved float4s
      const int b0 = slot * 4;
      float acc[8][4];
#pragma unroll
      for (int r = 0; r < 8; ++r)
#pragma unroll
        for (int i = 0; i < 4; ++i) acc[r][i] = 0.f;
      const float4* xh4 = (const float4*)(wsf + XH);
#pragma unroll
      for (int q = 0; q < 12; ++q) {
        const int kq = q*32 + ks;      // consecutive lanes -> consecutive float4s
        float4 xv[4];
#pragma unroll
        for (int i = 0; i < 4; ++i) xv[i] = xh4[(size_t)(b0+i)*384 + kq];
#pragma unroll
        for (int r = 0; r < 8; ++r) {
          float4 wv = *(const float4*)(&lds.a.Wg[r][kq*4]);
#pragma unroll
          for (int i = 0; i < 4; ++i)
            acc[r][i] += wv.x*xv[i].x + wv.y*xv[i].y + wv.z*xv[i].z + wv.w*xv[i].w;
        }
      }
#pragma unroll
      for (int r = 0; r < 8; ++r)
#pragma unroll
        for (int i = 0; i < 4; ++i) {
          float v = acc[r][i];
          v += __shfl_xor(v, 16); v += __shfl_xor(v, 8); v += __shfl_xor(v, 4);
          v += __shfl_xor(v, 2);  v += __shfl_xor(v, 1);
          acc[r][i] = v;
        }
      if (ks == 0) {
#pragma unroll
        for (int r = 0; r < 8; ++r)
#pragma unroll
          for (int i = 0; i < 4; ++i)
            wsf[GATES + (size_t)(b0+i)*2048 + j0 + r] = acc[r][i] + lds.a.gb[r];
      }
    } else if (s > 0) {
      const int blk2 = blk - 256, v0 = blk2*20;
      if (v0 < Vv) {
        for (int i = tid; i < 640; i += NT) {
          int b = i / 20, vi = i - b*20;
          out[(size_t)(s-1)*160000 + (size_t)b*5000 + v0 + vi] =
              wsf[LOGITS + (size_t)b*5120 + v0 + vi] - wsf[MB_ + b] - wsf[LSB_ + b];
        }
      }
    }
    gsync(wsu, blk, tid, myGen);

    // ============ Phase 2: LSTM pointwise + attention (all 512 blocks) =======
    {
      const int b = blk >> 4, tc = blk & 15;
      float* hs = scr;  // [512]
      const size_t gbase = GATES + (size_t)b*2048;
      const int cr = CBUF + (s & 1)*16384 + b*512;
      const int cw = CBUF + ((s & 1) ^ 1)*16384 + b*512;
      for (int u = tid; u < 512; u += NT) {
        float gi = wsf[gbase + u],        gf = wsf[gbase + 512 + u];
        float gg = wsf[gbase + 1024 + u], go = wsf[gbase + 1536 + u];
        float co = wsf[cr + u];
        float cn = sigm(gf)*co + sigm(gi)*tanhf(gg);
        float hn = sigm(go)*tanhf(cn);
        hs[u] = hn;
        if (tc == 0) { wsf[cw + u] = cn; wsf[XH + (size_t)b*1536 + 1024 + u] = hn; }
      }
      __syncthreads();
      const int w = tid >> 6, ln = tid & 63;   // wave<->head, lane<->t
      const int t0 = tc * 64;
      float e = 0.f;
      {
        const float4* lf4 = (const float4*)(LF + ((size_t)(b*Tv + t0 + ln))*512 + w*128);
        const float4* h4  = (const float4*)(hs + w*128);
#pragma unroll
        for (int q = 0; q < 32; ++q) {
          float4 f = lf4[q]; float4 hh = h4[q];
          e += f.x*hh.x + f.y*hh.y + f.z*hh.z + f.w*hh.w;
        }
      }
      float m = e;
#pragma unroll
      for (int off = 32; off; off >>= 1) m = fmaxf(m, __shfl_xor(m, off));
      float p = expf(e - m);
      float l = p;
#pragma unroll
      for (int off = 32; off; off >>= 1) l += __shfl_xor(l, off);
      scr[512 + w*64 + ln] = p;
      if (w == 3) wsf[E3 + (size_t)b*1024 + t0 + ln] = e;
      // ctx pass: lane <-> d-pair (coalesced LF re-read)
      float c0 = 0.f, c1 = 0.f;
      {
        const float2* lf2 = (const float2*)LF;
        const size_t base2 = (size_t)(b*Tv + t0)*256 + w*64 + ln;
#pragma unroll 8
        for (int i = 0; i < 64; ++i) {
          float pp = scr[512 + w*64 + i];
          float2 f = lf2[base2 + (size_t)i*256];
          c0 += pp*f.x; c1 += pp*f.y;
        }
      }
      float* pr = wsf + PART + (size_t)((b*4 + w)*16 + tc)*130;
      ((float2*)(pr + 2))[ln] = make_float2(c0, c1);
      if (ln == 0) { pr[0] = m; pr[1] = l; }
      __syncthreads();
      if (tid == 0) {
        __builtin_amdgcn_fence(__ATOMIC_RELEASE, "agent");
        unsigned old = add_rlx(&wsu[ACNT + b*16], 1u);
        sint[0] = (old == (unsigned)(s*16 + 15));
      }
      __syncthreads();
      if (sint[0]) {                       // last arriver merges the 16 chunks
        if (tid == 0) __builtin_amdgcn_fence(__ATOMIC_ACQUIRE, "agent");
        __syncthreads();
        const int w2 = tid >> 6, ln2 = tid & 63;
        const size_t pb = PART + (size_t)(b*4 + w2)*16*130;
        float M = -1e30f;
#pragma unroll
        for (int i = 0; i < 16; ++i) M = fmaxf(M, wsf[pb + i*130]);
        float L = 0.f;
#pragma unroll
        for (int i = 0; i < 16; ++i) L += wsf[pb + i*130 + 1] * expf(wsf[pb + i*130] - M);
        float cc0 = 0.f, cc1 = 0.f;
#pragma unroll
        for (int i = 0; i < 16; ++i) {
          float sc = expf(wsf[pb + i*130] - M);
          float2 cx = ((const float2*)(wsf + pb + i*130 + 2))[ln2];
          cc0 += sc*cx.x; cc1 += sc*cx.y;
        }
        float invL = 1.f / L;
        ((float2*)(wsf + XH + (size_t)b*1536 + 512 + w2*128))[ln2] = make_float2(cc0*invL, cc1*invL);
        if (ln2 == 0) { scr[768 + w2*2] = M; scr[769 + w2*2] = L; }
        __syncthreads();
        float M3 = scr[768 + 6], iL3 = 1.f / scr[768 + 7];
        for (int i = tid; i < 1024; i += NT)
          out[(size_t)10240000 + ((size_t)(s*32 + b))*1024 + i] =
              expf(wsf[E3 + (size_t)b*1024 + i] - M3) * iL3;
      }
    }
    gsync(wsu, blk, tid, myGen);

    // ============ Phase 3: MLP hid = relu([h,ctx] @ Wp^T + bp) ===============
    if (blk >= 256) {
      const int blk2 = blk - 256, rp0 = blk2*2;
      const int bb = tid & 31, ks = tid >> 5;        // 8 K-windows of 128
      const int kb = ks * 128;
      const int xbase = (ks < 4) ? (1024 + kb) : kb; // concat: k<512 -> h, else ctx
      const float4* xr = (const float4*)(wsf + XH + (size_t)bb*1536 + xbase);
      const float4* w0 = (const float4*)(&lds.b.Wp[0][kb]);
      const float4* w1 = (const float4*)(&lds.b.Wp[1][kb]);
      float a0 = 0.f, a1 = 0.f;
#pragma unroll
      for (int q = 0; q < 32; ++q) {
        float4 xv = xr[q]; float4 wv0 = w0[q], wv1 = w1[q];
        a0 += wv0.x*xv.x + wv0.y*xv.y + wv0.z*xv.z + wv0.w*xv.w;
        a1 += wv1.x*xv.x + wv1.y*xv.y + wv1.z*xv.z + wv1.w*xv.w;
      }
      scr[ks*32 + bb] = a0; scr[256 + ks*32 + bb] = a1;
      __syncthreads();
      if (tid < 64) {
        int r = tid >> 5, b2 = tid & 31;
        float ssum = 0.f;
#pragma unroll
        for (int j = 0; j < 8; ++j) ssum += scr[r*256 + j*32 + b2];
        ssum += lds.b.bpl[r];
        wsf[HID + (size_t)b2*512 + rp0 + r] = fmaxf(ssum, 0.f);
      }
      __syncthreads();
    }
    gsync(wsu, blk, tid, myGen);

    // ============ Phase 4: logits + log-softmax/argmax partials + merge ======
    if (blk >= 256) {
      const int blk2 = blk - 256;
      if (blk2 < 250) {
        const int v0 = blk2 * 20;
        const int bb = tid >> 3, ks = tid & 7;       // lane<->K-window of 64
        float4 xr[16];
        const float4* hb = (const float4*)(wsf + HID + (size_t)bb*512 + ks*64);
#pragma unroll
        for (int q = 0; q < 16; ++q) xr[q] = hb[q];
        float lgv[20];
#pragma unroll
        for (int vi = 0; vi < 20; ++vi) {
          float a = 0.f;
          const float4* wr = (const float4*)(&lds.b.Wc[vi][ks*64]);
#pragma unroll
          for (int q = 0; q < 16; ++q) {
            float4 wv = wr[q];
            a += wv.x*xr[q].x + wv.y*xr[q].y + wv.z*xr[q].z + wv.w*xr[q].w;
          }
          a += __shfl_xor(a, 1); a += __shfl_xor(a, 2); a += __shfl_xor(a, 4);
          lgv[vi] = a + lds.b.bcl[vi];
        }
        if (ks == 0) {
#pragma unroll
          for (int vi = 0; vi < 20; ++vi)
            wsf[LOGITS + (size_t)bb*5120 + v0 + vi] = lgv[vi];
        }
        float mych = lgv[0]; int ami = 0;
#pragma unroll
        for (int vi = 1; vi < 20; ++vi)
          if (lgv[vi] > mych) { mych = lgv[vi]; ami = vi; }
        float sume = 0.f;
#pragma unroll
        for (int vi = 0; vi < 20; ++vi) sume += expf(lgv[vi] - mych);
        if (ks == 0) {
          wsf[PM + bb*256 + blk2] = mych;
          wsf[PSUM + bb*256 + blk2] = sume;
          ((int*)(wsf + PIDX))[bb*256 + blk2] = v0 + ami;
        }
      }
      __syncthreads();
      if (tid == 0) __builtin_amdgcn_fence(__ATOMIC_RELEASE, "agent");
      __syncthreads();
      if (tid < 32) {
        unsigned old = 0xffffffffu;
        if (blk2 < 250) old = add_rlx(&wsu[LCNT + tid*16], 1u);
        sint[1 + tid] = (old == (unsigned)(s*250 + 249));
      }
      __syncthreads();
      for (int b2 = 0; b2 < 32; ++b2) {
        if (sint[1 + b2]) {                 // last arriver for batch b2 merges
          if (tid == 0) __builtin_amdgcn_fence(__ATOMIC_ACQUIRE, "agent");
          __syncthreads();
          float mv = -1e30f, sv = 0.f; int iv = 0x7fffffff;
          if (tid < 250) {
            mv = wsf[PM + b2*256 + tid];
            sv = wsf[PSUM + b2*256 + tid];
            iv = ((const int*)(wsf + PIDX))[b2*256 + tid];
          }
          scr[tid] = mv; sint[40 + tid] = iv;
          __syncthreads();
          for (int off = 128; off; off >>= 1) {
            if (tid < off) {
              float m2 = scr[tid + off]; int i2 = sint[40 + tid + off];
              if (m2 > scr[tid] || (m2 == scr[tid] && i2 < sint[40 + tid])) {
                scr[tid] = m2; sint[40 + tid] = i2;
              }
            }
            __syncthreads();
          }
          float M = scr[0]; int tok = sint[40];
          __syncthreads();
          scr[tid] = sv * expf(mv - M);
          __syncthreads();
          for (int off = 128; off; off >>= 1) {
            if (tid < off) scr[tid] += scr[tid + off];
            __syncthreads();
          }
          if (tid == 0) { wsf[MB_ + b2] = M; wsf[LSB_ + b2] = logf(scr[0]); }
          for (int i = tid; i < 512; i += NT)
            wsf[XH + (size_t)b2*1536 + i] = Emb[(size_t)tok*512 + i];
          __syncthreads();
        }
      }
    }
    gsync(wsu, blk, tid, myGen);
  }

  // ---------------- epilogue: finalize step 63's log-softmax ----------------
  if (blk >= 256) {
    const int blk2 = blk - 256, v0 = blk2*20;
    if (v0 < Vv) {
      for (int i = tid; i < 640; i += NT) {
        int b = i / 20, vi = i - b*20;
        out[(size_t)63*160000 + (size_t)b*5000 + v0 + vi] =
            wsf[LOGITS + (size_t)b*5120 + v0 + vi] - wsf[MB_ + b] - wsf[LSB_ + b];
      }
    }
  }
}

extern "C" void kernel_launch(void* const* d_in, const int* in_sizes, int n_in,
                              void* d_out, int out_size, void* d_ws, size_t ws_size,
                              hipStream_t stream) {
  (void)in_sizes; (void)n_in; (void)out_size; (void)ws_size;
  const float* LF  = (const float*)d_in[0];
  const float* Emb = (const float*)d_in[1];
  const float* Wih = (const float*)d_in[2];
  const float* Whh = (const float*)d_in[3];
  const float* bih = (const float*)d_in[4];
  const float* bhh = (const float*)d_in[5];
  const float* Wp  = (const float*)d_in[6];
  const float* bp  = (const float*)d_in[7];
  const float* Wc  = (const float*)d_in[8];
  const float* bc  = (const float*)d_in[9];
  float* out = (float*)d_out;
  unsigned* wsu = (unsigned*)d_ws;
  float* wsf = (float*)d_ws + WSU;

  speller_init<<<32, NT, 0, stream>>>(LF, Emb, wsf, wsu);
  speller_main<<<NB, NT, 0, stream>>>(LF, Emb, Wih, Whh, bih, bhh, Wp, bp, Wc, bc,
                                      out, wsu, wsf);
}

// Round 3
// 12394.035 us; speedup vs baseline: 5.1548x; 1.4740x over previous
//
#include <hip/hip_runtime.h>
#include <math.h>
#include <stdint.h>

// ---------------------------------------------------------------------------
// Speller decoder, persistent kernel, 512 blocks x 256 threads.
// R3: ZERO cache-maintenance coherence. All cross-block data moves through
// relaxed AGENT-scope atomics (global_load/store sc0 sc1 -> coherent L3);
// read-only inputs (LF, weights, Emb) use plain cached loads and stay warm
// in L2 (no more buffer_inv). Barriers = relaxed monotonic counters; the
// vmcnt drain in __syncthreads() is the release. LSTM fused into the gate
// GEMM (block owns i,f,g,o rows of 2 units; c stays in registers all 64
// steps). Phase-4 LDS interleaved -> conflict-free. All math fp32.
// ---------------------------------------------------------------------------

#define NB 512
#define NT 256

constexpr int Tv = 1024, Vv = 5000, STEPS = 64;

// ---- u32 counter region (all monotonic, zeroed by init kernel) ----
constexpr int MCNT = 0;               // master barrier counter
constexpr int GEN  = 16;              // barrier generation
constexpr int GCNT = 64;              // 32 group counters, stride 16
constexpr int GFLG = 1024;            // 32 group release flags, stride 32
constexpr int ACNT = 2048;            // 32 attn-merge counters, stride 16
constexpr int LCNT = 2560;            // 32 logits-merge counters, stride 16
constexpr int WSU  = 4096;

// ---- float region offsets (wsf = (float*)ws + WSU) ----
constexpr int XH   = 0;                    // [32][1024] = emb(512) | ctx(512)
constexpr int HB   = XH + 32*1024;         // [2][32][512] h double-buffer
constexpr int HID  = HB + 2*32*512;        // [32][512]
constexpr int PART = HID + 32*512;         // [32][4][16][130] attn partials
constexpr int E3   = PART + 32*4*16*130;   // [32][1024] head-3 energies
constexpr int PM   = E3 + 32*1024;         // [32][256] chunk max
constexpr int PSUM = PM + 32*256;          // [32][256] chunk sumexp
constexpr int PIDX = PSUM + 32*256;        // [32][256] chunk argmax (int)
constexpr int MLS  = PIDX + 32*256;        // [32][2] (max, lse)

__device__ __forceinline__ float sigm(float x) { return 1.f / (1.f + expf(-x)); }

// ---- coherent (L3, sc0 sc1) access helpers: relaxed agent atomics ----
__device__ __forceinline__ float ld4(const float* p) {
  return __hip_atomic_load(const_cast<float*>(p), __ATOMIC_RELAXED, __HIP_MEMORY_SCOPE_AGENT);
}
__device__ __forceinline__ void st4(float* p, float v) {
  __hip_atomic_store(p, v, __ATOMIC_RELAXED, __HIP_MEMORY_SCOPE_AGENT);
}
__device__ __forceinline__ float2 ld8(const float* p) {
  unsigned long long u = __hip_atomic_load(
      reinterpret_cast<unsigned long long*>(const_cast<float*>(p)),
      __ATOMIC_RELAXED, __HIP_MEMORY_SCOPE_AGENT);
  union { unsigned long long u; float2 f; } c; c.u = u; return c.f;
}
__device__ __forceinline__ void st8(float* p, float2 v) {
  union { float2 f; unsigned long long u; } c; c.f = v;
  __hip_atomic_store(reinterpret_cast<unsigned long long*>(p), c.u,
                     __ATOMIC_RELAXED, __HIP_MEMORY_SCOPE_AGENT);
}
__device__ __forceinline__ int ld4i(const int* p) {
  return (int)__hip_atomic_load(reinterpret_cast<unsigned*>(const_cast<int*>(p)),
                                __ATOMIC_RELAXED, __HIP_MEMORY_SCOPE_AGENT);
}
__device__ __forceinline__ void st4i(int* p, int v) {
  __hip_atomic_store(reinterpret_cast<unsigned*>(p), (unsigned)v,
                     __ATOMIC_RELAXED, __HIP_MEMORY_SCOPE_AGENT);
}
__device__ __forceinline__ unsigned ld_rlx(unsigned* p) {
  return __hip_atomic_load(p, __ATOMIC_RELAXED, __HIP_MEMORY_SCOPE_AGENT);
}
__device__ __forceinline__ void st_rlx(unsigned* p, unsigned v) {
  __hip_atomic_store(p, v, __ATOMIC_RELAXED, __HIP_MEMORY_SCOPE_AGENT);
}
__device__ __forceinline__ unsigned add_rlx(unsigned* p, unsigned v) {
  return __hip_atomic_fetch_add(p, v, __ATOMIC_RELAXED, __HIP_MEMORY_SCOPE_AGENT);
}

// Device barrier: NO cache ops. __syncthreads drains vmcnt (sc1 stores are
// then in L3 = globally visible); counters/flags are relaxed sc1 atomics.
__device__ __forceinline__ void gsync(unsigned* wsu, int blk, int tid, unsigned& myGen) {
  __syncthreads();
  if (tid == 0) {
    const unsigned target = ++myGen;
    const int grp = blk >> 4;
    unsigned o = add_rlx(&wsu[GCNT + grp*16], 1u);
    if (o == target*16u - 1u) {
      unsigned o2 = add_rlx(&wsu[MCNT], 1u);
      if (o2 == target*32u - 1u) st_rlx(&wsu[GEN], target);
    }
    if ((blk & 15) == 0) {
      while (ld_rlx(&wsu[GEN]) != target) __builtin_amdgcn_s_sleep(2);
      st_rlx(&wsu[GFLG + grp*32], target);
    } else {
      while (ld_rlx(&wsu[GFLG + grp*32]) != target) __builtin_amdgcn_s_sleep(2);
    }
  }
  __syncthreads();
}

__global__ void speller_init(const float* __restrict__ LF, const float* __restrict__ Emb,
                             float* __restrict__ wsf, unsigned* __restrict__ wsu) {
  int b = blockIdx.x;
  for (int i = threadIdx.x; i < 512; i += NT) {
    st4(wsf + XH + b*1024 + i,       Emb[i]);                    // emb row 0
    st4(wsf + XH + b*1024 + 512 + i, LF[(size_t)b*Tv*512 + i]);  // ctx0 = LF[b,0,:]
    st4(wsf + HB + b*512 + i,        0.f);                       // h0 (buffer 0)
  }
  if (b == 0) for (int i = threadIdx.x; i < WSU; i += NT) st_rlx(wsu + i, 0u);
}

struct LdsA { float Wg[8][1536]; float gb[8]; };   // gate rows: i,i,f,f,g,g,o,o of units 2j,2j+1
struct LdsB { float Wc[20][512]; float Wp[2][1024]; float bcl[20]; float bpl[2]; };
union  LdsU { LdsA a; LdsB b; };

__launch_bounds__(NT, 2)
__global__ void speller_main(const float* __restrict__ LF, const float* __restrict__ Emb,
                             const float* __restrict__ Wih, const float* __restrict__ Whh,
                             const float* __restrict__ bih, const float* __restrict__ bhh,
                             const float* __restrict__ Wp,  const float* __restrict__ bp,
                             const float* __restrict__ Wc,  const float* __restrict__ bc,
                             float* __restrict__ out, unsigned* __restrict__ wsu,
                             float* __restrict__ wsf) {
  const int blk = blockIdx.x, tid = threadIdx.x;
  unsigned myGen = 0;
  __shared__ LdsU lds;
  __shared__ float scr[784];
  __shared__ int  sint[300];

  // ---------------- one-time LDS weight preload (plain cached loads) -------
  if (blk < 256) {
    const int u0 = blk * 2;
    for (int idx = tid; idx < 8*1536; idx += NT) {
      int r = idx / 1536, k = idx - r*1536;
      int g = r >> 1, uu = r & 1;
      int row = g*512 + u0 + uu;
      lds.a.Wg[r][k] = (k < 1024) ? Wih[(size_t)row*1024 + k]
                                  : Whh[(size_t)row*512 + (k-1024)];
    }
    if (tid < 8) {
      int g = tid >> 1, uu = tid & 1, row = g*512 + u0 + uu;
      lds.a.gb[tid] = bih[row] + bhh[row];
    }
  } else {
    const int blk2 = blk - 256, v0 = blk2*20, rp0 = blk2*2;
    if (v0 < Vv) {
      for (int idx = tid; idx < 20*512; idx += NT) {
        int vi = idx >> 9, k = idx & 511;
        lds.b.Wc[vi][k] = Wc[(size_t)(v0+vi)*512 + k];
      }
      if (tid < 20) lds.b.bcl[tid] = bc[v0+tid];
    }
    for (int idx = tid; idx < 2048; idx += NT) {
      int r = idx >> 10, k = idx & 1023;
      lds.b.Wp[r][k] = Wp[(size_t)(rp0+r)*1024 + k];
    }
    if (tid < 2) lds.b.bpl[tid] = bp[rp0+tid];
  }
  __syncthreads();

  float c_reg[2][4];                 // cell state, lives in registers all run
#pragma unroll
  for (int uu = 0; uu < 2; ++uu)
#pragma unroll
    for (int i = 0; i < 4; ++i) c_reg[uu][i] = 0.f;
  float lgv[20];                     // logits carried phase4 -> next phase1

#pragma unroll 1
  for (int s = 0; s < STEPS; ++s) {
    const int rbuf = s & 1, wbuf = (s + 1) & 1;

    // ===== Phase 1: gates GEMM + fused LSTM (blk<256) | out-write (>=256) ==
    if (blk < 256) {
      const int u0 = blk * 2;
      const int slot = tid >> 5, ks = tid & 31, b0 = slot * 4;
      float acc[8][4];
#pragma unroll
      for (int r = 0; r < 8; ++r)
#pragma unroll
        for (int i = 0; i < 4; ++i) acc[r][i] = 0.f;
      const float* x1 = wsf + XH;                  // [32][1024] emb|ctx
      const float* x2 = wsf + HB + rbuf*16384;     // [32][512]  h
#pragma unroll 2
      for (int q = 0; q < 8; ++q) {                // k in [0,1024): emb|ctx
        const int kq = q*32 + ks;
        float2 xa[4], xb[4];
#pragma unroll
        for (int i = 0; i < 4; ++i) {
          const float* p = x1 + (size_t)(b0+i)*1024 + kq*4;
          xa[i] = ld8(p); xb[i] = ld8(p + 2);
        }
#pragma unroll
        for (int r = 0; r < 8; ++r) {
          float4 wv = *(const float4*)(&lds.a.Wg[r][kq*4]);
#pragma unroll
          for (int i = 0; i < 4; ++i)
            acc[r][i] += wv.x*xa[i].x + wv.y*xa[i].y + wv.z*xb[i].x + wv.w*xb[i].y;
        }
      }
#pragma unroll 2
      for (int q = 0; q < 4; ++q) {                // k in [1024,1536): h
        const int kq = q*32 + ks;
        float2 xa[4], xb[4];
#pragma unroll
        for (int i = 0; i < 4; ++i) {
          const float* p = x2 + (size_t)(b0+i)*512 + kq*4;
          xa[i] = ld8(p); xb[i] = ld8(p + 2);
        }
#pragma unroll
        for (int r = 0; r < 8; ++r) {
          float4 wv = *(const float4*)(&lds.a.Wg[r][1024 + kq*4]);
#pragma unroll
          for (int i = 0; i < 4; ++i)
            acc[r][i] += wv.x*xa[i].x + wv.y*xa[i].y + wv.z*xb[i].x + wv.w*xb[i].y;
        }
      }
#pragma unroll
      for (int r = 0; r < 8; ++r)
#pragma unroll
        for (int i = 0; i < 4; ++i) {
          float v = acc[r][i];
          v += __shfl_xor(v, 16); v += __shfl_xor(v, 8); v += __shfl_xor(v, 4);
          v += __shfl_xor(v, 2);  v += __shfl_xor(v, 1);
          acc[r][i] = v + lds.a.gb[r];
        }
      // fused LSTM pointwise (rows: i=uu, f=2+uu, g=4+uu, o=6+uu)
      float hnew[2][4];
#pragma unroll
      for (int uu = 0; uu < 2; ++uu)
#pragma unroll
        for (int i = 0; i < 4; ++i) {
          float cn = sigm(acc[2+uu][i]) * c_reg[uu][i]
                   + sigm(acc[uu][i]) * tanhf(acc[4+uu][i]);
          c_reg[uu][i] = cn;
          hnew[uu][i] = sigm(acc[6+uu][i]) * tanhf(cn);
        }
      if (ks == 0) {
#pragma unroll
        for (int i = 0; i < 4; ++i)
          st8(wsf + HB + wbuf*16384 + (size_t)(b0+i)*512 + u0,
              make_float2(hnew[0][i], hnew[1][i]));
      }
    } else if (s > 0) {
      const int blk2 = blk - 256;
      if (blk2 < 250) {
        const int v0 = blk2 * 20, bb = tid >> 3, ks = tid & 7;
        if (ks == 0) {
          float2 ml = ld8(wsf + MLS + 2*bb);
          float sub = ml.x + ml.y;
#pragma unroll
          for (int vi = 0; vi < 20; ++vi)
            out[(size_t)(s-1)*160000 + (size_t)bb*5000 + v0 + vi] = lgv[vi] - sub;
        }
      }
    }
    gsync(wsu, blk, tid, myGen);

    // ============ Phase 2: attention (all 512 blocks) ========================
    {
      const int b = blk >> 4, tc = blk & 15;
      float* hs = scr;  // [512]
      {
        float2 hv = ld8(wsf + HB + wbuf*16384 + (size_t)b*512 + tid*2);
        hs[tid*2] = hv.x; hs[tid*2+1] = hv.y;
      }
      __syncthreads();
      const int w = tid >> 6, ln = tid & 63;   // wave<->head, lane<->t
      const int t0 = tc * 64;
      float e = 0.f;
      {
        const float4* lf4 = (const float4*)(LF + ((size_t)(b*Tv + t0 + ln))*512 + w*128);
        const float4* h4  = (const float4*)(hs + w*128);
#pragma unroll
        for (int q = 0; q < 32; ++q) {
          float4 f = lf4[q]; float4 hh = h4[q];
          e += f.x*hh.x + f.y*hh.y + f.z*hh.z + f.w*hh.w;
        }
      }
      float m = e;
#pragma unroll
      for (int off = 32; off; off >>= 1) m = fmaxf(m, __shfl_xor(m, off));
      float p = expf(e - m);
      float l = p;
#pragma unroll
      for (int off = 32; off; off >>= 1) l += __shfl_xor(l, off);
      scr[512 + w*64 + ln] = p;
      if (w == 3) st4(wsf + E3 + (size_t)b*1024 + t0 + ln, e);
      __syncthreads();   // probs visible in LDS
      float c0 = 0.f, c1 = 0.f;
      {
        const float2* lf2 = (const float2*)LF;
        const size_t base2 = (size_t)(b*Tv + t0)*256 + w*64 + ln;
#pragma unroll 8
        for (int i = 0; i < 64; ++i) {
          float pp = scr[512 + w*64 + i];
          float2 f = lf2[base2 + (size_t)i*256];
          c0 += pp*f.x; c1 += pp*f.y;
        }
      }
      float* pr = wsf + PART + (size_t)((b*4 + w)*16 + tc)*130;
      st8(pr + 2 + 2*ln, make_float2(c0, c1));
      if (ln == 0) st8(pr, make_float2(m, l));
      __syncthreads();   // drains vmcnt: all this block's partials are in L3
      if (tid == 0) {
        unsigned old = add_rlx(&wsu[ACNT + b*16], 1u);
        sint[0] = (old == (unsigned)(s*16 + 15));
      }
      __syncthreads();
      if (sint[0]) {                       // last arriver merges the 16 chunks
        const int w2 = tid >> 6, ln2 = tid & 63;
        const float* pb = wsf + PART + (size_t)(b*4 + w2)*16*130;
        float mv[16];
#pragma unroll
        for (int i = 0; i < 16; ++i) { float2 t = ld8(pb + i*130); mv[i] = t.x; scr[776/1 - 776 + 0] = 0.f; scr[0] = scr[0]; (void)t; }
        // (re-load pairs cleanly)
        float M = -1e30f;
        float lv[16];
#pragma unroll
        for (int i = 0; i < 16; ++i) { float2 t = ld8(pb + i*130); mv[i] = t.x; lv[i] = t.y; M = fmaxf(M, t.x); }
        float L = 0.f;
        float sc[16];
#pragma unroll
        for (int i = 0; i < 16; ++i) { sc[i] = expf(mv[i] - M); L += lv[i] * sc[i]; }
        float cc0 = 0.f, cc1 = 0.f;
#pragma unroll
        for (int i = 0; i < 16; ++i) {
          float2 cx = ld8(pb + i*130 + 2 + 2*ln2);
          cc0 += sc[i]*cx.x; cc1 += sc[i]*cx.y;
        }
        float invL = 1.f / L;
        st8(wsf + XH + (size_t)b*1024 + 512 + w2*128 + 2*ln2,
            make_float2(cc0*invL, cc1*invL));
        if (ln2 == 0) { scr[768 + w2*2] = M; scr[769 + w2*2] = L; }
        __syncthreads();
        float M3 = scr[768 + 6], iL3 = 1.f / scr[768 + 7];
        for (int i = tid; i < 1024; i += NT)
          out[(size_t)10240000 + ((size_t)(s*32 + b))*1024 + i] =
              expf(ld4(wsf + E3 + (size_t)b*1024 + i) - M3) * iL3;
      }
    }
    gsync(wsu, blk, tid, myGen);

    // ============ Phase 3: MLP hid = relu([h,ctx] @ Wp^T + bp) ===============
    if (blk >= 256) {
      const int blk2 = blk - 256, rp0 = blk2*2;
      const int bb = tid & 31, ks = tid >> 5;        // 8 K-windows of 128
      const float* xr = (ks < 4) ? (wsf + HB + wbuf*16384 + (size_t)bb*512 + ks*128)
                                 : (wsf + XH + (size_t)bb*1024 + (ks-4)*128 + 512);
      const int kb = ks * 128;
      const float4* w0 = (const float4*)(&lds.b.Wp[0][kb]);
      const float4* w1 = (const float4*)(&lds.b.Wp[1][kb]);
      float a0 = 0.f, a1 = 0.f;
#pragma unroll 8
      for (int q = 0; q < 32; ++q) {
        float2 xva = ld8(xr + q*4), xvb = ld8(xr + q*4 + 2);
        float4 wv0 = w0[q], wv1 = w1[q];
        a0 += wv0.x*xva.x + wv0.y*xva.y + wv0.z*xvb.x + wv0.w*xvb.y;
        a1 += wv1.x*xva.x + wv1.y*xva.y + wv1.z*xvb.x + wv1.w*xvb.y;
      }
      scr[ks*32 + bb] = a0; scr[256 + ks*32 + bb] = a1;
      __syncthreads();
      if (tid < 64) {
        int r = tid >> 5, b2 = tid & 31;
        float ssum = 0.f;
#pragma unroll
        for (int j = 0; j < 8; ++j) ssum += scr[r*256 + j*32 + b2];
        ssum += lds.b.bpl[r];
        st4(wsf + HID + (size_t)b2*512 + rp0 + r, fmaxf(ssum, 0.f));
      }
      __syncthreads();
    }
    gsync(wsu, blk, tid, myGen);

    // ============ Phase 4: logits + softmax/argmax partials + merge ==========
    if (blk >= 256) {
      const int blk2 = blk - 256;
      if (blk2 < 250) {
        const int v0 = blk2 * 20;
        const int bb = tid >> 3, ks = tid & 7;       // interleaved K chunks
        float4 xr[16];
        const float* hb = wsf + HID + (size_t)bb*512;
#pragma unroll
        for (int q = 0; q < 16; ++q) {
          const float* p = hb + (q*8 + ks)*4;
          float2 a = ld8(p), b2v = ld8(p + 2);
          xr[q] = make_float4(a.x, a.y, b2v.x, b2v.y);
        }
#pragma unroll
        for (int vi = 0; vi < 20; ++vi) {
          float a = 0.f;
#pragma unroll
          for (int q = 0; q < 16; ++q) {
            float4 wv = *(const float4*)(&lds.b.Wc[vi][(q*8 + ks)*4]);
            a += wv.x*xr[q].x + wv.y*xr[q].y + wv.z*xr[q].z + wv.w*xr[q].w;
          }
          a += __shfl_xor(a, 1); a += __shfl_xor(a, 2); a += __shfl_xor(a, 4);
          lgv[vi] = a + lds.b.bcl[vi];
        }
        float mych = lgv[0]; int ami = 0;
#pragma unroll
        for (int vi = 1; vi < 20; ++vi)
          if (lgv[vi] > mych) { mych = lgv[vi]; ami = vi; }
        float sume = 0.f;
#pragma unroll
        for (int vi = 0; vi < 20; ++vi) sume += expf(lgv[vi] - mych);
        if (ks == 0) {
          st4(wsf + PM + bb*256 + blk2, mych);
          st4(wsf + PSUM + bb*256 + blk2, sume);
          st4i((int*)(wsf + PIDX) + bb*256 + blk2, v0 + ami);
        }
      }
      __syncthreads();   // drain: partials in L3
      if (tid < 32) {
        unsigned old = 0xffffffffu;
        if (blk2 < 250) old = add_rlx(&wsu[LCNT + tid*16], 1u);
        sint[1 + tid] = (old == (unsigned)(s*250 + 249));
      }
      __syncthreads();
      for (int b2 = 0; b2 < 32; ++b2) {
        if (sint[1 + b2]) {                 // last arriver for batch b2 merges
          float mv = -1e30f, sv = 0.f; int iv = 0x7fffffff;
          if (tid < 250) {
            mv = ld4(wsf + PM + b2*256 + tid);
            sv = ld4(wsf + PSUM + b2*256 + tid);
            iv = ld4i((const int*)(wsf + PIDX) + b2*256 + tid);
          }
          scr[tid] = mv; sint[40 + tid] = iv;
          __syncthreads();
          for (int off = 128; off; off >>= 1) {
            if (tid < off) {
              float m2 = scr[tid + off]; int i2 = sint[40 + tid + off];
              if (m2 > scr[tid] || (m2 == scr[tid] && i2 < sint[40 + tid])) {
                scr[tid] = m2; sint[40 + tid] = i2;
              }
            }
            __syncthreads();
          }
          float M = scr[0]; int tok = sint[40];
          __syncthreads();
          scr[tid] = sv * expf(mv - M);
          __syncthreads();
          for (int off = 128; off; off >>= 1) {
            if (tid < off) scr[tid] += scr[tid + off];
            __syncthreads();
          }
          if (tid == 0) st8(wsf + MLS + 2*b2, make_float2(M, logf(scr[0])));
          for (int i = tid; i < 256; i += NT) {
            const float2* er = (const float2*)(Emb + (size_t)tok*512);
            st8(wsf + XH + (size_t)b2*1024 + 2*i, er[i]);
          }
          __syncthreads();
        }
      }
    }
    gsync(wsu, blk, tid, myGen);
  }

  // ---------------- epilogue: step 63's log-softmax from registers ----------
  if (blk >= 256) {
    const int blk2 = blk - 256;
    if (blk2 < 250) {
      const int v0 = blk2 * 20, bb = tid >> 3, ks = tid & 7;
      if (ks == 0) {
        float2 ml = ld8(wsf + MLS + 2*bb);
        float sub = ml.x + ml.y;
#pragma unroll
        for (int vi = 0; vi < 20; ++vi)
          out[(size_t)63*160000 + (size_t)bb*5000 + v0 + vi] = lgv[vi] - sub;
      }
    }
  }
}

extern "C" void kernel_launch(void* const* d_in, const int* in_sizes, int n_in,
                              void* d_out, int out_size, void* d_ws, size_t ws_size,
                              hipStream_t stream) {
  (void)in_sizes; (void)n_in; (void)out_size; (void)ws_size;
  const float* LF  = (const float*)d_in[0];
  const float* Emb = (const float*)d_in[1];
  const float* Wih = (const float*)d_in[2];
  const float* Whh = (const float*)d_in[3];
  const float* bih = (const float*)d_in[4];
  const float* bhh = (const float*)d_in[5];
  const float* Wp  = (const float*)d_in[6];
  const float* bp  = (const float*)d_in[7];
  const float* Wc  = (const float*)d_in[8];
  const float* bc  = (const float*)d_in[9];
  float* out = (float*)d_out;
  unsigned* wsu = (unsigned*)d_ws;
  float* wsf = (float*)d_ws + WSU;

  speller_init<<<32, NT, 0, stream>>>(LF, Emb, wsf, wsu);
  speller_main<<<NB, NT, 0, stream>>>(LF, Emb, Wih, Whh, bih, bhh, Wp, bp, Wc, bc,
                                      out, wsu, wsf);
}